// Round 7
// baseline (59.262 us; speedup 1.0000x reference)
//
#include <hip/hip_runtime.h>

// YOLOv1 loss forward, MI355X.
// preds/labels: (16384, 7, 7, 30) fp32, cell = 30 contiguous floats.
// R1 (42.5us): two 30.7KB LDS buffers, BLOCK=256, float4 copy staging.
// R2 (341us): reg-array staging -> scratch spill. R3 (142us): p[30] -> scratch.
// R4 (251us): fence+acq-rel-counter finish: ~35ns x blocks serialized L2 ops.
// R5 (37.4us): R1 + global_load_lds width=16. Main kernel at ~6.2 TB/s eff.
// R6 (41.4us): BLOCK=128/5 blocks/CU: occupancy 20% but slower -> BW-pinned,
//              occupancy refuted as binder. BLOCK=256 is the optimum.
// R7: R5 main kernel + fire-and-forget atomicAdd(out, part/BATCH) per block
//     (relaxed, no fences -- R4's cost was the fence protocol, not atomics).
//     Kills the 2nd launch (~4us). memsetAsync zeroes out[0] each call since
//     atomics accumulate across graph replays.

#define NCELLS   802816                // 16384*7*7
#define CH       30
#define BLOCK    256
#define NBLOCKS  (NCELLS / BLOCK)      // 3136, exact
#define NVEC     (BLOCK * CH / 4)      // 1920 float4 per array per block
#define INV_BATCH 6.103515625e-05f     // 1/16384, exact in fp32

#define GLOAD16(gaddr, laddr)                                                  \
    __builtin_amdgcn_global_load_lds(                                          \
        (const __attribute__((address_space(1))) unsigned int*)(gaddr),        \
        (__attribute__((address_space(3))) unsigned int*)(laddr), 16, 0, 0)

__device__ __forceinline__ float sq(float x) { return x * x; }

__device__ __forceinline__ float iou_f(float bx, float by, float bw, float bh,
                                       float lx, float ly, float lw, float lh) {
    float area1 = bw * bh;
    float area2 = lw * lh;
    float max_left  = fmaxf(bx - bw * 0.5f, lx - lw * 0.5f);
    float min_right = fminf(bx + bw * 0.5f, lx + lw * 0.5f);
    float max_top   = fmaxf(by - bh * 0.5f, ly - lh * 0.5f);
    float min_bot   = fminf(by + bh * 0.5f, ly + lh * 0.5f);
    float iw = min_right - max_left;
    float ih = min_bot - max_top;
    float inter = iw * ih;
    float iou = inter / (area1 + area2 - inter);
    return (iw > 0.f && ih > 0.f) ? iou : 0.f;
}

__global__ __launch_bounds__(BLOCK) void yolo_loss_main(
        const float* __restrict__ preds,
        const float* __restrict__ labels,
        float* __restrict__ out) {
    __shared__ alignas(16) float sp[BLOCK * CH];   // 30720 B
    __shared__ alignas(16) float sl[BLOCK * CH];   // 30720 B
    __shared__ float warp_s[4];

    const int tid = threadIdx.x;
    const long base4 = (long)blockIdx.x * NVEC;
    const float4* p4 = reinterpret_cast<const float4*>(preds) + base4;
    const float4* l4 = reinterpret_cast<const float4*>(labels) + base4;
    float4* sp4 = reinterpret_cast<float4*>(sp);
    float4* sl4 = reinterpret_cast<float4*>(sl);

    // Async global->LDS staging, width 16. LDS dest linear in lane order
    // (lane l -> wave_base + l*16). Tail guard (idx<1920 -> tid<128) is
    // wave-uniform (2-wave boundary).
    #pragma unroll
    for (int i = 0; i < 8; ++i) {
        int idx = i * BLOCK + tid;
        if (idx < NVEC) {
            GLOAD16(p4 + idx, sp4 + idx);
            GLOAD16(l4 + idx, sl4 + idx);
        }
    }
    __syncthreads();   // vmcnt(0) drain + barrier

    // Compute directly from LDS — named scalars only (no per-thread arrays).
    const float* P = sp + tid * CH;
    const float* L = sl + tid * CH;

    float p0 = P[0], p1 = P[1], p2 = P[2], p3 = P[3], pc1 = P[4];
    float q0 = P[5], q1 = P[6], q2 = P[7], q3 = P[8], pc2 = P[9];
    float l0 = L[0], l1 = L[1], l2 = L[2], l3 = L[3], lobj = L[4];

    const bool obj = (lobj == 1.0f);

    float cls = 0.f;
    #pragma unroll
    for (int c = 10; c < CH; ++c) {
        float d = L[c] - P[c];
        cls += d * d;
    }

    float iou1 = iou_f(p0, p1, p2, p3, l0, l1, l2, l3);
    float iou2 = iou_f(q0, q1, q2, q3, l0, l1, l2, l3);
    const bool sel1 = iou1 > iou2;

    float xy1 = sq(l0 - p0) + sq(l1 - p1);
    float xy2 = sq(l0 - q0) + sq(l1 - q1);

    float sl2 = sqrtf(l2), sl3 = sqrtf(l3);
    float wh1 = sq(sl2 - sqrtf(p2)) + sq(sl3 - sqrtf(p3));
    float wh2 = sq(sl2 - sqrtf(q2)) + sq(sl3 - sqrtf(q3));

    float o1 = sq(iou1 - pc1);
    float o2 = sq(iou2 - pc2);

    float n1 = pc2 * pc2;   // sel1 responsible -> penalize other box's conf
    float n2 = pc1 * pc1;

    float contrib;
    if (obj) {
        float xyt = sel1 ? xy1 : xy2;
        float wht = sel1 ? wh1 : wh2;
        float ot  = sel1 ? o1  : o2;
        float nt  = sel1 ? n1  : n2;
        contrib = 5.0f * xyt + wht + ot + 0.5f * nt + cls;
    } else {
        contrib = 0.5f * (pc1 * pc1 + pc2 * pc2);
    }

    // wave-64 reduction -> block partial
    float v = contrib;
    #pragma unroll
    for (int off = 32; off > 0; off >>= 1)
        v += __shfl_down(v, off, 64);
    if ((tid & 63) == 0) warp_s[tid >> 6] = v;
    __syncthreads();
    if (tid == 0) {
        float part = warp_s[0] + warp_s[1] + warp_s[2] + warp_s[3];
        atomicAdd(out, part * INV_BATCH);   // relaxed, no fence, fire-and-forget
    }
}

extern "C" void kernel_launch(void* const* d_in, const int* in_sizes, int n_in,
                              void* d_out, int out_size, void* d_ws, size_t ws_size,
                              hipStream_t stream) {
    const float* preds  = (const float*)d_in[0];
    const float* labels = (const float*)d_in[1];
    float* out = (float*)d_out;

    // Atomics accumulate across graph replays -> zero out[0] every call.
    hipMemsetAsync(out, 0, sizeof(float), stream);
    yolo_loss_main<<<NBLOCKS, BLOCK, 0, stream>>>(preds, labels, out);
}

// Round 8
// 35.447 us; speedup vs baseline: 1.6719x; 1.6719x over previous
//
#include <hip/hip_runtime.h>

// YOLOv1 loss forward, MI355X.
// preds/labels: (16384, 7, 7, 30) fp32, cell = 30 contiguous floats.
// R1 (42.5us): LDS float4-copy staging. R2 (341us)/R3 (142us): reg arrays ->
//   scratch spill. R4 (251us): fence+counter finish (serialized L2 ops).
// R5 (37.4us): global_load_lds w16, block-wide stage->barrier->compute.
// R6 (41.4us): BLOCK=128 refuted occupancy as binder.
// R7 (59.3us): 3136 same-address device atomics = +22us. Two-kernel stands.
// R8: per-wave self-staging: each wave gload_lds's exactly its own 64 cells,
//     so the mid-kernel __syncthreads (collective vmcnt(0) drain = duty-cycle
//     stall) is eliminated; 8 waves/CU stagger stage/compute naturally.

#define NCELLS   802816                // 16384*7*7
#define CH       30
#define BLOCK    256
#define NBLOCKS  (NCELLS / BLOCK)      // 3136, exact
#define BLK_CHUNKS (BLOCK * CH * 4 / 16)   // 1920 16B chunks per array per block
#define WAVE_CHUNKS 480                // 64 cells * 120B / 16
#define BATCH    16384.0

#define GLOAD16(gaddr, laddr)                                                  \
    __builtin_amdgcn_global_load_lds(                                          \
        (const __attribute__((address_space(1))) unsigned int*)(gaddr),        \
        (__attribute__((address_space(3))) unsigned int*)(laddr), 16, 0, 0)

__device__ __forceinline__ float sq(float x) { return x * x; }

__device__ __forceinline__ float iou_f(float bx, float by, float bw, float bh,
                                       float lx, float ly, float lw, float lh) {
    float area1 = bw * bh;
    float area2 = lw * lh;
    float max_left  = fmaxf(bx - bw * 0.5f, lx - lw * 0.5f);
    float min_right = fminf(bx + bw * 0.5f, lx + lw * 0.5f);
    float max_top   = fmaxf(by - bh * 0.5f, ly - lh * 0.5f);
    float min_bot   = fminf(by + bh * 0.5f, ly + lh * 0.5f);
    float iw = min_right - max_left;
    float ih = min_bot - max_top;
    float inter = iw * ih;
    float iou = inter / (area1 + area2 - inter);
    return (iw > 0.f && ih > 0.f) ? iou : 0.f;
}

__global__ __launch_bounds__(BLOCK) void yolo_loss_main(
        const float* __restrict__ preds,
        const float* __restrict__ labels,
        float* __restrict__ partials) {
    __shared__ alignas(16) float sp[BLOCK * CH];   // 30720 B
    __shared__ alignas(16) float sl[BLOCK * CH];   // 30720 B
    __shared__ float warp_s[4];

    const int tid  = threadIdx.x;
    const int wid  = tid >> 6;
    const int lane = tid & 63;

    const long blk_chunk = (long)blockIdx.x * BLK_CHUNKS;
    const float4* p4 = reinterpret_cast<const float4*>(preds) + blk_chunk;
    const float4* l4 = reinterpret_cast<const float4*>(labels) + blk_chunk;
    float4* sp4 = reinterpret_cast<float4*>(sp);
    float4* sl4 = reinterpret_cast<float4*>(sl);

    // Per-wave self-staging: wave w owns chunks [480w, 480w+480) of each
    // array = its own 64 cells. 7 full iters + 1 half-wave iter per array.
    // LDS dest stays linear in lane order (base + lane*16) per instruction.
    const int wbase = wid * WAVE_CHUNKS;
    #pragma unroll
    for (int k = 0; k < 7; ++k) {
        int c = wbase + k * 64 + lane;
        GLOAD16(p4 + c, sp4 + c);
    }
    if (lane < 32) {
        int c = wbase + 448 + lane;
        GLOAD16(p4 + c, sp4 + c);
    }
    #pragma unroll
    for (int k = 0; k < 7; ++k) {
        int c = wbase + k * 64 + lane;
        GLOAD16(l4 + c, sl4 + c);
    }
    if (lane < 32) {
        int c = wbase + 448 + lane;
        GLOAD16(l4 + c, sl4 + c);
    }
    // Per-wave drain only — NO block-wide barrier. Each wave reads only the
    // LDS region it staged itself.
    asm volatile("s_waitcnt vmcnt(0)" ::: "memory");

    // Compute directly from LDS — named scalars only (no per-thread arrays).
    const float* P = sp + tid * CH;
    const float* L = sl + tid * CH;

    float p0 = P[0], p1 = P[1], p2 = P[2], p3 = P[3], pc1 = P[4];
    float q0 = P[5], q1 = P[6], q2 = P[7], q3 = P[8], pc2 = P[9];
    float l0 = L[0], l1 = L[1], l2 = L[2], l3 = L[3], lobj = L[4];

    const bool obj = (lobj == 1.0f);

    float cls = 0.f;
    #pragma unroll
    for (int c = 10; c < CH; ++c) {
        float d = L[c] - P[c];
        cls += d * d;
    }

    float iou1 = iou_f(p0, p1, p2, p3, l0, l1, l2, l3);
    float iou2 = iou_f(q0, q1, q2, q3, l0, l1, l2, l3);
    const bool sel1 = iou1 > iou2;

    float xy1 = sq(l0 - p0) + sq(l1 - p1);
    float xy2 = sq(l0 - q0) + sq(l1 - q1);

    float sl2 = sqrtf(l2), sl3 = sqrtf(l3);
    float wh1 = sq(sl2 - sqrtf(p2)) + sq(sl3 - sqrtf(p3));
    float wh2 = sq(sl2 - sqrtf(q2)) + sq(sl3 - sqrtf(q3));

    float o1 = sq(iou1 - pc1);
    float o2 = sq(iou2 - pc2);

    float n1 = pc2 * pc2;   // sel1 responsible -> penalize other box's conf
    float n2 = pc1 * pc1;

    float contrib;
    if (obj) {
        float xyt = sel1 ? xy1 : xy2;
        float wht = sel1 ? wh1 : wh2;
        float ot  = sel1 ? o1  : o2;
        float nt  = sel1 ? n1  : n2;
        contrib = 5.0f * xyt + wht + ot + 0.5f * nt + cls;
    } else {
        contrib = 0.5f * (pc1 * pc1 + pc2 * pc2);
    }

    // wave-64 reduction -> per-wave partial
    float v = contrib;
    #pragma unroll
    for (int off = 32; off > 0; off >>= 1)
        v += __shfl_down(v, off, 64);
    if (lane == 0) warp_s[wid] = v;
    __syncthreads();   // only barrier in the kernel (loads long drained)
    if (tid == 0)
        partials[blockIdx.x] = warp_s[0] + warp_s[1] + warp_s[2] + warp_s[3];
}

__global__ __launch_bounds__(256) void yolo_loss_final(
        const float* __restrict__ partials,
        float* __restrict__ out) {
    __shared__ double s[4];
    const int tid = threadIdx.x;
    // 3136 floats = 784 float4; thread t handles t, t+256, t+512 and tail.
    const float4* p4 = reinterpret_cast<const float4*>(partials);
    double acc = 0.0;
    #pragma unroll
    for (int k = 0; k < 3; ++k) {
        float4 v = p4[k * 256 + tid];
        acc += (double)v.x + (double)v.y + (double)v.z + (double)v.w;
    }
    if (tid < 16) {
        float4 v = p4[768 + tid];
        acc += (double)v.x + (double)v.y + (double)v.z + (double)v.w;
    }
    #pragma unroll
    for (int off = 32; off > 0; off >>= 1)
        acc += __shfl_down(acc, off, 64);
    if ((tid & 63) == 0) s[tid >> 6] = acc;
    __syncthreads();
    if (tid == 0) out[0] = (float)((s[0] + s[1] + s[2] + s[3]) / BATCH);
}

extern "C" void kernel_launch(void* const* d_in, const int* in_sizes, int n_in,
                              void* d_out, int out_size, void* d_ws, size_t ws_size,
                              hipStream_t stream) {
    const float* preds  = (const float*)d_in[0];
    const float* labels = (const float*)d_in[1];
    float* out      = (float*)d_out;
    float* partials = (float*)d_ws;   // 3136 floats = 12.5 KB

    yolo_loss_main<<<NBLOCKS, BLOCK, 0, stream>>>(preds, labels, partials);
    yolo_loss_final<<<1, 256, 0, stream>>>(partials, out);
}